// Round 8
// baseline (146.716 us; speedup 1.0000x reference)
//
#include <hip/hip_runtime.h>

// SSIM loss, FUSED per-wave MFMA kernel (gfx950).
// R17: barrier-free restructure. R16 post-mortem: dur invariant ~47-50us
//   across traffic -45%, occupancy +50%, VALU -60% => block-level barrier
//   convoy is the bottleneck (all pipes <25%, waves phase-locked).
//   Now each WAVE independently does one 16x16 output tile:
//     8x dwordx4 loads (32x32 padded window, ONE vmcnt wait)
//     -> H-pass MFMA (5 fields x 2 stripes)
//     -> transpose via WAVE-PRIVATE LDS ping-pong (no __syncthreads:
//        same-wave DS ordering + compiler lgkmcnt suffice)
//     -> V-pass MFMA -> packed-f32 SSIM epilogue -> in-wave reduce
//     -> partial[tid] (one f32 per wave, 49152 total = 192KB ws).
//   Index math inherited unchanged from the verified R16 kernel.

namespace {
constexpr int IMG   = 512;
constexpr int NCH   = 48;              // 16 * 3
constexpr int TPX   = IMG / 16;        // 32 tiles per row
constexpr int NTILE = TPX * TPX * NCH; // 49152 wave-tiles
constexpr int NBLK  = NTILE / 4;       // 12288 blocks (4 indep waves each)
constexpr int RS    = 40;              // p-dim stride, f16 units: 80B rows,
                                       // 16B-aligned, dword-stride 20 => good
                                       // bank spread for b128/b64 access

constexpr float Wf[11] = {
    0.00102838f, 0.00759876f, 0.03600077f, 0.10936069f, 0.21300554f,
    0.26601172f,
    0.21300554f, 0.10936069f, 0.03600077f, 0.00759876f, 0.00102838f };

constexpr float band_wc(int d) {       // W[d] for d in [0,11), else 0
    return (d >= 0 && d < 11) ? Wf[d] : 0.f;
}

// constexpr f32 -> f16 bits, round-to-nearest-even (matches runtime cast).
constexpr unsigned short f2h(float f) {
    if (f == 0.f) return 0;
    unsigned u = __builtin_bit_cast(unsigned, f);
    int  he = int((u >> 23) & 0xff) - 127 + 15;
    unsigned hm   = (u & 0x7fffff) >> 13;
    unsigned rest = u & 0x1fff;
    if (rest > 0x1000 || (rest == 0x1000 && (hm & 1))) ++hm;
    return (unsigned short)((unsigned(he) << 10) + hm);
}

struct Tabs { unsigned short a[64][8]; unsigned short b[64][8]; };
constexpr Tabs build_tabs() {
    Tabs t{};
    for (int lane = 0; lane < 64; ++lane) {
        const int nr = lane & 15, quad = lane >> 4;
        for (int jj = 0; jj < 8; ++jj) {
            const int k = quad * 8 + jj;
            t.a[lane][jj] = f2h(band_wc(k - nr));       // V-pass A: W[k-m]
            t.b[lane][jj] = f2h(band_wc(k - nr - 3));   // H-pass B: W[k-n-3]
        }
    }
    return t;
}
}

__device__ __constant__ __align__(16) Tabs g_tabs = build_tabs();

typedef _Float16 half8 __attribute__((ext_vector_type(8)));
typedef _Float16 half4v __attribute__((ext_vector_type(4)));
typedef _Float16 h2 __attribute__((ext_vector_type(2)));
typedef float float4v __attribute__((ext_vector_type(4)));
typedef float float2v __attribute__((ext_vector_type(2)));

__device__ inline h2 pk(float a, float b) {
    auto v = __builtin_amdgcn_cvt_pkrtz(a, b);
    h2 r;
    __builtin_memcpy(&r, &v, sizeof(r));
    return r;
}

union H8 { half8 v; h2 p[4]; };

__global__ __launch_bounds__(256, 6) void ssim_fused_kernel(
    const float* __restrict__ pred, const float* __restrict__ tgt,
    float* __restrict__ partial)
{
    // wave-private transpose scratch: [wave][pingpong slot][x][p], 10 KB
    __shared__ __align__(16) _Float16 hf[4][2][16][RS];

    const int t    = threadIdx.x;
    const int w    = t >> 6;
    const int lane = t & 63;
    const int nr   = lane & 15;
    const int quad = lane >> 4;

    const int tid  = blockIdx.x * 4 + w;   // global wave-tile id
    const int img  = tid >> 10;            // 1024 tiles per plane
    const int tile = tid & 1023;
    const int tx   = (tile & 31) * 16;     // horiz-adjacent waves share rows
    const int ty   = (tile >> 5) * 16;

    const float* __restrict__ p = pred + (size_t)img * (IMG * IMG);
    const float* __restrict__ q = tgt  + (size_t)img * (IMG * IMG);

    const half8 Aband = *(const half8*)(g_tabs.a[lane]);
    const half8 Bband = *(const half8*)(g_tabs.b[lane]);
    const float4v zf = {0.f, 0.f, 0.f, 0.f};
    const half8 z8 = {};

    const int cb  = tx - 8 + (quad << 3);      // frag col base
    const int cbc = min(max(cb, 0), IMG - 8);
    const bool okc = ((unsigned)cb <= (unsigned)(IMG - 8));

    // ---- both stripes' 8 dwordx4 issued together: ONE latency exposure ----
    float4 xa[2], xb[2], ya[2], yb[2];
    bool ok[2];
    #pragma unroll
    for (int s = 0; s < 2; ++s) {
        const int gy  = ty + 16 * s + nr - 5;
        const int gyc = min(max(gy, 0), IMG - 1);
        ok[s] = ((unsigned)gy < (unsigned)IMG) && okc;
        const float* rp = p + gyc * IMG + cbc;
        const float* rq = q + gyc * IMG + cbc;
        xa[s] = *(const float4*)rp;
        xb[s] = *(const float4*)(rp + 4);
        ya[s] = *(const float4*)rq;
        yb[s] = *(const float4*)(rq + 4);
    }

    // ---- cvt to f16 fragments (frees f32 payload) ----
    half8 fx[2], fy[2];
    #pragma unroll
    for (int s = 0; s < 2; ++s) {
        H8 ax, ay;
        ax.p[0] = pk(xa[s].x, xa[s].y); ax.p[1] = pk(xa[s].z, xa[s].w);
        ax.p[2] = pk(xb[s].x, xb[s].y); ax.p[3] = pk(xb[s].z, xb[s].w);
        ay.p[0] = pk(ya[s].x, ya[s].y); ay.p[1] = pk(ya[s].z, ya[s].w);
        ay.p[2] = pk(yb[s].x, yb[s].y); ay.p[3] = pk(yb[s].z, yb[s].w);
        if (!ok[s]) { ax.v = z8; ay.v = z8; }
        fx[s] = ax.v;
        fy[s] = ay.v;
    }

    // H-pass D: col(lane&15)=x, row(4*quad+reg)=p within stripe.
    // store transposed: hf[w][slot][x=nr][p=16s+4quad+reg] (b64)
    const int wr = quad << 2;
    auto hwrite = [&](int slot, int s, float4v d) {
        h2 lo = pk(d[0], d[1]);
        h2 hi = pk(d[2], d[3]);
        half4v hh = {lo[0], lo[1], hi[0], hi[1]};
        *(half4v*)&hf[w][slot][nr][16 * s + wr] = hh;
    };
    // V-pass B frag: lane(nr,quad) needs x=nr, p=8*quad..+7 (b128)
    auto hread = [&](int slot) -> half8 {
        return *(const half8*)&hf[w][slot][nr][quad << 3];
    };
    auto HM = [&](half8 a) {
        return __builtin_amdgcn_mfma_f32_16x16x32_f16(a, Bband, zf, 0, 0, 0);
    };
    auto VM = [&](half8 b) {
        return __builtin_amdgcn_mfma_f32_16x16x32_f16(Aband, b, zf, 0, 0, 0);
    };

    float4v acc[5];
    // pass 1: mu_x (slot0), mu_y (slot1)
    hwrite(0, 0, HM(fx[0]));  hwrite(0, 1, HM(fx[1]));
    hwrite(1, 0, HM(fy[0]));  hwrite(1, 1, HM(fy[1]));
    acc[0] = VM(hread(0));
    acc[1] = VM(hread(1));
    // pass 2: E[x2] (slot0), E[y2] (slot1)  (WAR vs pass1 reads: program
    // order + in-order per-wave DS pipe; compiler keeps load<store on alias)
    hwrite(0, 0, HM(fx[0] * fx[0]));  hwrite(0, 1, HM(fx[1] * fx[1]));
    hwrite(1, 0, HM(fy[0] * fy[0]));  hwrite(1, 1, HM(fy[1] * fy[1]));
    acc[2] = VM(hread(0));
    acc[3] = VM(hread(1));
    // pass 3: E[xy] (slot0)
    hwrite(0, 0, HM(fx[0] * fy[0]));  hwrite(0, 1, HM(fx[1] * fy[1]));
    acc[4] = VM(hread(0));

    // ---- packed-f32 SSIM epilogue (acc rows = out rows ty+4q+reg, col tx+nr)
    constexpr float C1 = 1e-4f, C2 = 9e-4f;
    const float2v C1v = {C1, C1};
    const float2v C2v = {C2, C2};
    const float2v K12 = {C1 + C2, C1 + C2};
    float2v lsum2 = {0.f, 0.f};
    #pragma unroll
    for (int h = 0; h < 2; ++h) {
        float2v mx  = {acc[0][2*h], acc[0][2*h+1]};
        float2v my  = {acc[1][2*h], acc[1][2*h+1]};
        float2v ex2 = {acc[2][2*h], acc[2][2*h+1]};
        float2v ey2 = {acc[3][2*h], acc[3][2*h+1]};
        float2v exy = {acc[4][2*h], acc[4][2*h+1]};
        float2v P  = mx * my;
        float2v U  = mx * mx + my * my + C1v;
        float2v n1 = 2.f * P + C1v;
        float2v n2 = 2.f * (exy - P) + C2v;
        float2v num = n1 * n2;
        float2v e1 = (ex2 + ey2) - U + K12;
        float2v den = U * e1;
        float2v r = {__builtin_amdgcn_rcpf(den.x),
                     __builtin_amdgcn_rcpf(den.y)};
        lsum2 += num * r;
    }
    float lsum = lsum2.x + lsum2.y;

    #pragma unroll
    for (int off = 32; off > 0; off >>= 1)
        lsum += __shfl_down(lsum, off, 64);
    if (lane == 0) partial[tid] = lsum;       // per-wave, no block reduce
}

// Single-block finish: 1024 threads x 48 loads, deterministic tree reduce.
__global__ __launch_bounds__(1024) void ssim_finish(
    const float* __restrict__ partial, float* __restrict__ out)
{
    __shared__ float wred[16];
    const int t = threadIdx.x;
    float s = 0.f;
    #pragma unroll
    for (int i = 0; i < NTILE / 1024; ++i)
        s += partial[t + i * 1024];
    #pragma unroll
    for (int off = 32; off > 0; off >>= 1)
        s += __shfl_down(s, off, 64);
    if ((t & 63) == 0) wred[t >> 6] = s;
    __syncthreads();
    if (t == 0) {
        float acc = 0.f;
        #pragma unroll
        for (int i = 0; i < 16; ++i) acc += wred[i];
        out[0] = 1.f - acc * (1.f / (float)((long long)NCH * IMG * IMG));
    }
}

extern "C" void kernel_launch(void* const* d_in, const int* in_sizes, int n_in,
                              void* d_out, int out_size, void* d_ws, size_t ws_size,
                              hipStream_t stream)
{
    const float* pred = (const float*)d_in[0];
    const float* tgt  = (const float*)d_in[1];
    float* out     = (float*)d_out;
    float* partial = (float*)d_ws;    // NTILE floats = 192 KB

    ssim_fused_kernel<<<NBLK, 256, 0, stream>>>(pred, tgt, partial);
    ssim_finish<<<1, 1024, 0, stream>>>(partial, out);
}

// Round 10
// 130.020 us; speedup vs baseline: 1.1284x; 1.1284x over previous
//
#include <hip/hip_runtime.h>

// SSIM loss via MFMA band-matrix convolutions (gfx950).
// R18: wide-tile (128x32) LDS-staged restructure.
//   Post-mortems R14-R17: dur tracks LOGICAL request traffic (~5 TB/s ceiling,
//   64B segments from 16-row x 2KB-stride loads), not HBM bytes / occupancy /
//   VALU. Fix: stage 44x144 f32 window to LDS via global_load_lds (width 16,
//   cannot be compiler-sunk -> real MLP at last), then the verified
//   H-MFMA -> transpose -> V-MFMA pipeline entirely from LDS.
// R19 (this round, R18 never ran): correctness fixes found in re-audit:
//   (a) XOR slot-swizzle was NON-BIJECTIVE (36 slots % 8 != 0; slots 32-35
//       mapped to 36-39 = out of row) -> ROTATION swizzle mod 36, bijective
//       for any modulus; 8 distinct bank-starts per 8-row group => 2-way.
//   (b) RS 48 -> 56: 112B stride = 28 dwords mod 32 -> 8-bank cycle (2-way),
//       keeps 16B alignment for ds_read_b128 (48 was a 4-way pattern).
//   (c) staging tail EXEC-masked (L < 3168) instead of LDS pad.
//   LDS total 50688 + 14336 = 65024 B.

namespace {
constexpr int IMG   = 512;
constexpr int NCH   = 48;                  // 16 * 3
constexpr int TW    = 128;                 // tile cols
constexpr int TH    = 32;                  // tile rows
constexpr int WR    = 44;                  // staged window rows (ty-5..ty+38)
constexpr int WC    = 144;                 // staged window cols (tx-8..tx+135)
constexpr int SLOTS = WC / 4;              // 36 16B-slots per row
constexpr int TSLOT = WR * SLOTS;          // 1584 slots per tensor
constexpr int NLDI  = 50;                  // wave gload_lds instrs (3168 slots + tail mask)
constexpr int TPX   = IMG / TW;            // 4
constexpr int TPY   = IMG / TH;            // 16
constexpr int NBLK  = TPX * TPY * NCH;     // 3072
constexpr int NPART = NBLK * 4;            // 12288 (one f32 per wave)
constexpr int RS    = 56;                  // scratch p-stride (f16): 112B rows,
                                           // 16B-aligned, 28 dwords mod 32 -> 2-way
constexpr int SXN   = WR * WC;             // 6336 f32 per tensor

constexpr float Wf[11] = {
    0.00102838f, 0.00759876f, 0.03600077f, 0.10936069f, 0.21300554f,
    0.26601172f,
    0.21300554f, 0.10936069f, 0.03600077f, 0.00759876f, 0.00102838f };

constexpr float band_wc(int d) {           // W[d] for d in [0,11), else 0
    return (d >= 0 && d < 11) ? Wf[d] : 0.f;
}

// constexpr f32 -> f16 bits, round-to-nearest-even (matches runtime cast).
constexpr unsigned short f2h(float f) {
    if (f == 0.f) return 0;
    unsigned u = __builtin_bit_cast(unsigned, f);
    int  he = int((u >> 23) & 0xff) - 127 + 15;
    unsigned hm   = (u & 0x7fffff) >> 13;
    unsigned rest = u & 0x1fff;
    if (rest > 0x1000 || (rest == 0x1000 && (hm & 1))) ++hm;
    return (unsigned short)((unsigned(he) << 10) + hm);
}

struct Tabs { unsigned short a[64][8]; unsigned short b[64][8]; };
constexpr Tabs build_tabs() {
    Tabs t{};
    for (int lane = 0; lane < 64; ++lane) {
        const int nr = lane & 15, quad = lane >> 4;
        for (int jj = 0; jj < 8; ++jj) {
            const int k = quad * 8 + jj;
            t.a[lane][jj] = f2h(band_wc(k - nr));       // V-pass A: W[k-m]
            t.b[lane][jj] = f2h(band_wc(k - nr - 3));   // H-pass B: W[k-n-3]
        }
    }
    return t;
}
}

__device__ __constant__ __align__(16) Tabs g_tabs = build_tabs();

typedef _Float16 half8 __attribute__((ext_vector_type(8)));
typedef _Float16 half4v __attribute__((ext_vector_type(4)));
typedef _Float16 h2 __attribute__((ext_vector_type(2)));
typedef float float4v __attribute__((ext_vector_type(4)));
typedef float float2v __attribute__((ext_vector_type(2)));

__device__ inline h2 pk(float a, float b) {
    auto v = __builtin_amdgcn_cvt_pkrtz(a, b);
    h2 r;
    __builtin_memcpy(&r, &v, sizeof(r));
    return r;
}

union H8 { half8 v; h2 p[4]; };

// async global -> LDS, 16B per lane; dest = wave-uniform base + lane*16.
__device__ __forceinline__ void gl2l(const float* g, void* l) {
    __builtin_amdgcn_global_load_lds(
        (const __attribute__((address_space(1))) unsigned int*)g,
        (__attribute__((address_space(3))) unsigned int*)l, 16, 0, 0);
}

__global__ __launch_bounds__(256, 2) void ssim_tile_kernel(
    const float* __restrict__ pred, const float* __restrict__ tgt,
    float* __restrict__ partial)
{
    // staged window, f32, rotation-swizzled slots:
    //   LDS[tens][row][pos] = global slot (pos - row&7) mod 36
    __shared__ __align__(16) float sx[2 * SXN];              // 50688 B
    // wave-private transpose scratch [wave][pingpong][x][p]
    __shared__ __align__(16) _Float16 sc[4][2][16][RS];      // 14336 B

    const int t    = threadIdx.x;
    const int w    = t >> 6;
    const int lane = t & 63;
    const int nr   = lane & 15;
    const int quad = lane >> 4;

    const int bid  = blockIdx.x;
    const int img  = bid >> 6;             // 64 tiles per plane (4 x 16)
    const int tile = bid & 63;
    const int tx   = (tile & 3) * TW;
    const int ty   = (tile >> 2) * TH;

    const float* __restrict__ p = pred + (size_t)img * (IMG * IMG);
    const float* __restrict__ q = tgt  + (size_t)img * (IMG * IMG);

    // ===== P1: stage both tensors' windows via global_load_lds =====
    // linear LDS dest stream; global source PRE-ROTATED so that reads at
    // pos=(slot+row&7)%36 see logical slot order (both-sides rule, §5 #21).
    #pragma unroll
    for (int i = 0; i < 13; ++i) {
        const int j = i * 4 + w;           // wave-uniform instr index
        if (j < NLDI) {
            const int L = j * 64 + lane;
            if (L < 2 * TSLOT) {           // EXEC-mask the 32-lane tail
                const int tens = (L >= TSLOT) ? 1 : 0;
                const int Lt   = L - tens * TSLOT;
                const int row  = Lt / SLOTS;
                const int sp   = Lt - row * SLOTS;
                int sl = sp - (row & 7);
                if (sl < 0) sl += SLOTS;
                const int gy   = min(max(ty - 5 + row, 0), IMG - 1);
                const int gx   = min(max(tx - 8 + 4 * sl, 0), IMG - 4);
                const float* src = (tens ? q : p) + gy * IMG + gx;
                gl2l(src, (char*)sx + (size_t)j * 1024);
            }
        }
    }
    __syncthreads();   // drains vmcnt (gload_lds) + makes staging visible

    // ---- band fragments from the compile-time table ----
    const half8 Aband = *(const half8*)(g_tabs.a[lane]);
    const half8 Bband = *(const half8*)(g_tabs.b[lane]);
    const float4v zf = {0.f, 0.f, 0.f, 0.f};
    const half8 z8 = {};

    constexpr float C1 = 1e-4f, C2 = 9e-4f;
    const float2v C1v = {C1, C1};
    const float2v C2v = {C2, C2};
    const float2v K12 = {C1 + C2, C1 + C2};
    float2v lsum2 = {0.f, 0.f};

    // ===== P2: per-wave, 2 chunks of 16 output cols each =====
    #pragma unroll 1
    for (int cc = 0; cc < 2; ++cc) {
        const int c = w + 4 * cc;          // chunk 0..7
        // okc: zero frag when its 8 cols fall outside [0,512) (edge chunks)
        const bool okc_ = ((unsigned)(tx + 16 * c - 8 + 8 * quad)
                           <= (unsigned)(IMG - 8));

        // ---- read 6 A-frags (3 stripes x {x,y}) from staged window ----
        half8 fx[3], fy[3];
        #pragma unroll
        for (int s = 0; s < 3; ++s) {
            const int row  = 16 * s + nr;          // window row
            const int rowr = min(row, WR - 1);     // clamp addr (pad rows)
            const bool ok  = okc_ && (row < WR) &&
                             ((unsigned)(ty - 5 + row) < (unsigned)IMG);
            const int sl0 = 4 * c + 2 * quad;      // logical 16B slot (even)
            const int r7  = rowr & 7;
            int pos0 = sl0 + r7;     if (pos0 >= SLOTS) pos0 -= SLOTS;
            int pos1 = sl0 + 1 + r7; if (pos1 >= SLOTS) pos1 -= SLOTS;
            const float* b0 = sx + rowr * WC;
            const float* b1 = b0 + SXN;
            float4 xA = *(const float4*)(b0 + 4 * pos0);
            float4 xB = *(const float4*)(b0 + 4 * pos1);
            float4 yA = *(const float4*)(b1 + 4 * pos0);
            float4 yB = *(const float4*)(b1 + 4 * pos1);
            H8 ax, ay;
            ax.p[0] = pk(xA.x, xA.y); ax.p[1] = pk(xA.z, xA.w);
            ax.p[2] = pk(xB.x, xB.y); ax.p[3] = pk(xB.z, xB.w);
            ay.p[0] = pk(yA.x, yA.y); ay.p[1] = pk(yA.z, yA.w);
            ay.p[2] = pk(yB.x, yB.y); ay.p[3] = pk(yB.z, yB.w);
            if (!ok) { ax.v = z8; ay.v = z8; }
            fx[s] = ax.v;
            fy[s] = ay.v;
        }

        // ---- H-MFMA -> transposed scratch -> V-MFMA (ping-pong pairs) ----
        auto hw = [&](int slot, int s, float4v d) {
            h2 lo = pk(d[0], d[1]);
            h2 hi = pk(d[2], d[3]);
            half4v hh = {lo[0], lo[1], hi[0], hi[1]};
            *(half4v*)&sc[w][slot][nr][16 * s + 4 * quad] = hh;   // b64
        };
        auto rdv = [&](int slot, int pb) -> half8 {
            return *(const half8*)&sc[w][slot][nr][pb + 8 * quad]; // b128
        };
        #define HMA(a) __builtin_amdgcn_mfma_f32_16x16x32_f16((a), Bband, zf, 0, 0, 0)
        #define VMA(b) __builtin_amdgcn_mfma_f32_16x16x32_f16(Aband, (b), zf, 0, 0, 0)

        float4v a0[5], a1[5];   // V accumulators: out rows ty+.., ty+16+..
        // pass 1: x, y
        #pragma unroll
        for (int s = 0; s < 3; ++s) { hw(0, s, HMA(fx[s])); hw(1, s, HMA(fy[s])); }
        a0[0] = VMA(rdv(0, 0));  a1[0] = VMA(rdv(0, 16));
        a0[1] = VMA(rdv(1, 0));  a1[1] = VMA(rdv(1, 16));
        // pass 2: x*x, y*y (same-wave DS ordering: reads above precede writes)
        #pragma unroll
        for (int s = 0; s < 3; ++s) { hw(0, s, HMA(fx[s] * fx[s])); hw(1, s, HMA(fy[s] * fy[s])); }
        a0[2] = VMA(rdv(0, 0));  a1[2] = VMA(rdv(0, 16));
        a0[3] = VMA(rdv(1, 0));  a1[3] = VMA(rdv(1, 16));
        // pass 3: x*y
        #pragma unroll
        for (int s = 0; s < 3; ++s) { hw(0, s, HMA(fx[s] * fy[s])); }
        a0[4] = VMA(rdv(0, 0));  a1[4] = VMA(rdv(0, 16));

        // ---- packed-f32 SSIM epilogue for both 16-row halves ----
        #pragma unroll
        for (int v = 0; v < 2; ++v) {
            const float4v* A = v ? a1 : a0;
            #pragma unroll
            for (int h = 0; h < 2; ++h) {
                float2v mx  = {A[0][2*h], A[0][2*h+1]};
                float2v my  = {A[1][2*h], A[1][2*h+1]};
                float2v ex2 = {A[2][2*h], A[2][2*h+1]};
                float2v ey2 = {A[3][2*h], A[3][2*h+1]};
                float2v exy = {A[4][2*h], A[4][2*h+1]};
                float2v P  = mx * my;
                float2v U  = mx * mx + my * my + C1v;
                float2v n1 = 2.f * P + C1v;
                float2v n2 = 2.f * (exy - P) + C2v;
                float2v num = n1 * n2;
                float2v e1 = (ex2 + ey2) - U + K12;
                float2v den = U * e1;
                float2v r = {__builtin_amdgcn_rcpf(den.x),
                             __builtin_amdgcn_rcpf(den.y)};
                lsum2 += num * r;
            }
        }
        #undef HMA
        #undef VMA
    }

    float lsum = lsum2.x + lsum2.y;
    #pragma unroll
    for (int off = 32; off > 0; off >>= 1)
        lsum += __shfl_down(lsum, off, 64);
    if (lane == 0) partial[(bid << 2) + w] = lsum;
}

// Single-block finish: 1024 threads x 12 loads, deterministic tree reduce.
__global__ __launch_bounds__(1024) void ssim_finish(
    const float* __restrict__ partial, float* __restrict__ out)
{
    __shared__ float wred[16];
    const int t = threadIdx.x;
    float s = 0.f;
    #pragma unroll
    for (int i = 0; i < NPART / 1024; ++i)
        s += partial[t + i * 1024];
    #pragma unroll
    for (int off = 32; off > 0; off >>= 1)
        s += __shfl_down(s, off, 64);
    if ((t & 63) == 0) wred[t >> 6] = s;
    __syncthreads();
    if (t == 0) {
        float acc = 0.f;
        #pragma unroll
        for (int i = 0; i < 16; ++i) acc += wred[i];
        out[0] = 1.f - acc * (1.f / (float)((long long)NCH * IMG * IMG));
    }
}

extern "C" void kernel_launch(void* const* d_in, const int* in_sizes, int n_in,
                              void* d_out, int out_size, void* d_ws, size_t ws_size,
                              hipStream_t stream)
{
    const float* pred = (const float*)d_in[0];
    const float* tgt  = (const float*)d_in[1];
    float* out     = (float*)d_out;
    float* partial = (float*)d_ws;    // NPART floats = 48 KB

    ssim_tile_kernel<<<NBLK, 256, 0, stream>>>(pred, tgt, partial);
    ssim_finish<<<1, 1024, 0, stream>>>(partial, out);
}

// Round 12
// 127.833 us; speedup vs baseline: 1.1477x; 1.0171x over previous
//
#include <hip/hip_runtime.h>

// SSIM loss via MFMA band-matrix convolutions (gfx950).
// R19: 128x32 LDS-staged tile (global_load_lds + rotation swizzle):
//   41.6us tile; dur == FETCH/2.25TB/s => HBM duty-cycle bound at
//   2 blocks/CU (stage->barrier->compute serialization, duty ~1/3).
// R20: TW 64 for 4 blocks/CU overlap -- FAILED correctness (absmax 0.16):
//   RS was cut 56->40 but the transpose scratch p-dim needs 3*16=48 f16;
//   writes at 16*s+4*quad (max 47) overflowed into the next nr row.
// R21 (this round): RS=48 (96B rows, 16B-aligned; dword-starts
//   (24*nr+4*quad)%32 spread 64 lanes evenly over all 8 bank-groups ->
//   structural-min b128). LDS 28160+12288=40448B -> 4 blocks/CU exactly.
//   Everything else identical to R20.

namespace {
constexpr int IMG   = 512;
constexpr int NCH   = 48;                  // 16 * 3
constexpr int TW    = 64;                  // tile cols
constexpr int TH    = 32;                  // tile rows
constexpr int WR    = 44;                  // staged window rows (ty-5..ty+38)
constexpr int WC    = 80;                  // staged window cols (tx-8..tx+71)
constexpr int SLOTS = WC / 4;              // 20 16B-slots per row
constexpr int TSLOT = WR * SLOTS;          // 880 slots per tensor
constexpr int NSL   = 2 * TSLOT;           // 1760 slots total
constexpr int TPX   = IMG / TW;            // 8
constexpr int TPY   = IMG / TH;            // 16
constexpr int NBLK  = TPX * TPY * NCH;     // 6144
constexpr int NPART = NBLK * 4;            // 24576 (one f32 per wave)
constexpr int RS    = 48;                  // scratch p-stride (f16): >=48 REQUIRED
constexpr int SXN   = WR * WC;             // 3520 f32 per tensor

constexpr float Wf[11] = {
    0.00102838f, 0.00759876f, 0.03600077f, 0.10936069f, 0.21300554f,
    0.26601172f,
    0.21300554f, 0.10936069f, 0.03600077f, 0.00759876f, 0.00102838f };

constexpr float band_wc(int d) {           // W[d] for d in [0,11), else 0
    return (d >= 0 && d < 11) ? Wf[d] : 0.f;
}

// constexpr f32 -> f16 bits, round-to-nearest-even (matches runtime cast).
constexpr unsigned short f2h(float f) {
    if (f == 0.f) return 0;
    unsigned u = __builtin_bit_cast(unsigned, f);
    int  he = int((u >> 23) & 0xff) - 127 + 15;
    unsigned hm   = (u & 0x7fffff) >> 13;
    unsigned rest = u & 0x1fff;
    if (rest > 0x1000 || (rest == 0x1000 && (hm & 1))) ++hm;
    return (unsigned short)((unsigned(he) << 10) + hm);
}

struct Tabs { unsigned short a[64][8]; unsigned short b[64][8]; };
constexpr Tabs build_tabs() {
    Tabs t{};
    for (int lane = 0; lane < 64; ++lane) {
        const int nr = lane & 15, quad = lane >> 4;
        for (int jj = 0; jj < 8; ++jj) {
            const int k = quad * 8 + jj;
            t.a[lane][jj] = f2h(band_wc(k - nr));       // V-pass A: W[k-m]
            t.b[lane][jj] = f2h(band_wc(k - nr - 3));   // H-pass B: W[k-n-3]
        }
    }
    return t;
}
}

__device__ __constant__ __align__(16) Tabs g_tabs = build_tabs();

typedef _Float16 half8 __attribute__((ext_vector_type(8)));
typedef _Float16 half4v __attribute__((ext_vector_type(4)));
typedef _Float16 h2 __attribute__((ext_vector_type(2)));
typedef float float4v __attribute__((ext_vector_type(4)));
typedef float float2v __attribute__((ext_vector_type(2)));

__device__ inline h2 pk(float a, float b) {
    auto v = __builtin_amdgcn_cvt_pkrtz(a, b);
    h2 r;
    __builtin_memcpy(&r, &v, sizeof(r));
    return r;
}

union H8 { half8 v; h2 p[4]; };

// async global -> LDS, 16B per lane; dest = wave-uniform base + lane*16.
__device__ __forceinline__ void gl2l(const float* g, void* l) {
    __builtin_amdgcn_global_load_lds(
        (const __attribute__((address_space(1))) unsigned int*)g,
        (__attribute__((address_space(3))) unsigned int*)l, 16, 0, 0);
}

__global__ __launch_bounds__(256, 4) void ssim_tile_kernel(
    const float* __restrict__ pred, const float* __restrict__ tgt,
    float* __restrict__ partial)
{
    // staged window, f32, rotation-swizzled slots:
    //   LDS[tens][row][pos] = global slot (pos - row&7) mod 20
    __shared__ __align__(16) float sx[2 * SXN];              // 28160 B
    // wave-private transpose scratch [wave][pingpong][x][p]
    __shared__ __align__(16) _Float16 sc[4][2][16][RS];      // 12288 B

    const int t    = threadIdx.x;
    const int w    = t >> 6;
    const int lane = t & 63;
    const int nr   = lane & 15;
    const int quad = lane >> 4;

    const int bid  = blockIdx.x;
    const int img  = bid >> 7;             // 128 tiles per plane (8 x 16)
    const int tile = bid & 127;
    const int tx   = (tile & 7) * TW;
    const int ty   = (tile >> 3) * TH;

    const float* __restrict__ p = pred + (size_t)img * (IMG * IMG);
    const float* __restrict__ q = tgt  + (size_t)img * (IMG * IMG);

    // ===== P1: stage both tensors' windows via global_load_lds =====
    // linear LDS dest stream; global source PRE-ROTATED so that reads at
    // pos=(slot+row&7)%20 see logical slot order (both-sides rule, §5 #21).
    #pragma unroll
    for (int i = 0; i < 7; ++i) {
        const int j = i * 4 + w;           // wave-uniform instr index 0..27
        const int L = j * 64 + lane;
        if (L < NSL) {                     // EXEC-mask the 32-lane tail
            const int tens = (L >= TSLOT) ? 1 : 0;
            const int Lt   = L - tens * TSLOT;
            const int row  = Lt / SLOTS;
            const int sp   = Lt - row * SLOTS;
            int sl = sp - (row & 7);
            if (sl < 0) sl += SLOTS;
            const int gy   = min(max(ty - 5 + row, 0), IMG - 1);
            const int gx   = min(max(tx - 8 + 4 * sl, 0), IMG - 4);
            const float* src = (tens ? q : p) + gy * IMG + gx;
            gl2l(src, (char*)sx + (size_t)j * 1024);
        }
    }
    __syncthreads();   // drains vmcnt (gload_lds) + makes staging visible

    // ---- band fragments from the compile-time table ----
    const half8 Aband = *(const half8*)(g_tabs.a[lane]);
    const half8 Bband = *(const half8*)(g_tabs.b[lane]);
    const float4v zf = {0.f, 0.f, 0.f, 0.f};
    const half8 z8 = {};

    constexpr float C1 = 1e-4f, C2 = 9e-4f;
    const float2v C1v = {C1, C1};
    const float2v C2v = {C2, C2};
    const float2v K12 = {C1 + C2, C1 + C2};
    float2v lsum2 = {0.f, 0.f};

    // ===== P2: each wave owns chunk c = w (16 output cols) =====
    {
        const int c = w;
        // okc: zero frag when its 8 cols fall outside [0,512) (edge chunks)
        const bool okc_ = ((unsigned)(tx + 16 * c - 8 + 8 * quad)
                           <= (unsigned)(IMG - 8));

        // ---- read 6 A-frags (3 stripes x {x,y}) from staged window ----
        half8 fx[3], fy[3];
        #pragma unroll
        for (int s = 0; s < 3; ++s) {
            const int row  = 16 * s + nr;          // window row
            const int rowr = min(row, WR - 1);     // clamp addr (pad rows)
            const bool ok  = okc_ && (row < WR) &&
                             ((unsigned)(ty - 5 + row) < (unsigned)IMG);
            const int sl0 = 4 * c + 2 * quad;      // logical 16B slot (even)
            const int r7  = rowr & 7;
            int pos0 = sl0 + r7;     if (pos0 >= SLOTS) pos0 -= SLOTS;
            int pos1 = sl0 + 1 + r7; if (pos1 >= SLOTS) pos1 -= SLOTS;
            const float* b0 = sx + rowr * WC;
            const float* b1 = b0 + SXN;
            float4 xA = *(const float4*)(b0 + 4 * pos0);
            float4 xB = *(const float4*)(b0 + 4 * pos1);
            float4 yA = *(const float4*)(b1 + 4 * pos0);
            float4 yB = *(const float4*)(b1 + 4 * pos1);
            H8 ax, ay;
            ax.p[0] = pk(xA.x, xA.y); ax.p[1] = pk(xA.z, xA.w);
            ax.p[2] = pk(xB.x, xB.y); ax.p[3] = pk(xB.z, xB.w);
            ay.p[0] = pk(yA.x, yA.y); ay.p[1] = pk(yA.z, yA.w);
            ay.p[2] = pk(yB.x, yB.y); ay.p[3] = pk(yB.z, yB.w);
            if (!ok) { ax.v = z8; ay.v = z8; }
            fx[s] = ax.v;
            fy[s] = ay.v;
        }

        // ---- H-MFMA -> transposed scratch -> V-MFMA (ping-pong pairs) ----
        auto hw = [&](int slot, int s, float4v d) {
            h2 lo = pk(d[0], d[1]);
            h2 hi = pk(d[2], d[3]);
            half4v hh = {lo[0], lo[1], hi[0], hi[1]};
            *(half4v*)&sc[w][slot][nr][16 * s + 4 * quad] = hh;   // b64
        };
        auto rdv = [&](int slot, int pb) -> half8 {
            return *(const half8*)&sc[w][slot][nr][pb + 8 * quad]; // b128
        };
        #define HMA(a) __builtin_amdgcn_mfma_f32_16x16x32_f16((a), Bband, zf, 0, 0, 0)
        #define VMA(b) __builtin_amdgcn_mfma_f32_16x16x32_f16(Aband, (b), zf, 0, 0, 0)

        float4v a0[5], a1[5];   // V accumulators: out rows ty+.., ty+16+..
        // pass 1: x, y
        #pragma unroll
        for (int s = 0; s < 3; ++s) { hw(0, s, HMA(fx[s])); hw(1, s, HMA(fy[s])); }
        a0[0] = VMA(rdv(0, 0));  a1[0] = VMA(rdv(0, 16));
        a0[1] = VMA(rdv(1, 0));  a1[1] = VMA(rdv(1, 16));
        // pass 2: x*x, y*y (same-wave DS ordering: reads above precede writes)
        #pragma unroll
        for (int s = 0; s < 3; ++s) { hw(0, s, HMA(fx[s] * fx[s])); hw(1, s, HMA(fy[s] * fy[s])); }
        a0[2] = VMA(rdv(0, 0));  a1[2] = VMA(rdv(0, 16));
        a0[3] = VMA(rdv(1, 0));  a1[3] = VMA(rdv(1, 16));
        // pass 3: x*y
        #pragma unroll
        for (int s = 0; s < 3; ++s) { hw(0, s, HMA(fx[s] * fy[s])); }
        a0[4] = VMA(rdv(0, 0));  a1[4] = VMA(rdv(0, 16));

        // ---- packed-f32 SSIM epilogue for both 16-row halves ----
        #pragma unroll
        for (int v = 0; v < 2; ++v) {
            const float4v* A = v ? a1 : a0;
            #pragma unroll
            for (int h = 0; h < 2; ++h) {
                float2v mx  = {A[0][2*h], A[0][2*h+1]};
                float2v my  = {A[1][2*h], A[1][2*h+1]};
                float2v ex2 = {A[2][2*h], A[2][2*h+1]};
                float2v ey2 = {A[3][2*h], A[3][2*h+1]};
                float2v exy = {A[4][2*h], A[4][2*h+1]};
                float2v P  = mx * my;
                float2v U  = mx * mx + my * my + C1v;
                float2v n1 = 2.f * P + C1v;
                float2v n2 = 2.f * (exy - P) + C2v;
                float2v num = n1 * n2;
                float2v e1 = (ex2 + ey2) - U + K12;
                float2v den = U * e1;
                float2v r = {__builtin_amdgcn_rcpf(den.x),
                             __builtin_amdgcn_rcpf(den.y)};
                lsum2 += num * r;
            }
        }
        #undef HMA
        #undef VMA
    }

    float lsum = lsum2.x + lsum2.y;
    #pragma unroll
    for (int off = 32; off > 0; off >>= 1)
        lsum += __shfl_down(lsum, off, 64);
    if (lane == 0) partial[(bid << 2) + w] = lsum;
}

// Single-block finish: 1024 threads x 24 loads, deterministic tree reduce.
__global__ __launch_bounds__(1024) void ssim_finish(
    const float* __restrict__ partial, float* __restrict__ out)
{
    __shared__ float wred[16];
    const int t = threadIdx.x;
    float s = 0.f;
    #pragma unroll
    for (int i = 0; i < NPART / 1024; ++i)
        s += partial[t + i * 1024];
    #pragma unroll
    for (int off = 32; off > 0; off >>= 1)
        s += __shfl_down(s, off, 64);
    if ((t & 63) == 0) wred[t >> 6] = s;
    __syncthreads();
    if (t == 0) {
        float acc = 0.f;
        #pragma unroll
        for (int i = 0; i < 16; ++i) acc += wred[i];
        out[0] = 1.f - acc * (1.f / (float)((long long)NCH * IMG * IMG));
    }
}

extern "C" void kernel_launch(void* const* d_in, const int* in_sizes, int n_in,
                              void* d_out, int out_size, void* d_ws, size_t ws_size,
                              hipStream_t stream)
{
    const float* pred = (const float*)d_in[0];
    const float* tgt  = (const float*)d_in[1];
    float* out     = (float*)d_out;
    float* partial = (float*)d_ws;    // NPART floats = 96 KB

    ssim_tile_kernel<<<NBLK, 256, 0, stream>>>(pred, tgt, partial);
    ssim_finish<<<1, 1024, 0, stream>>>(partial, out);
}